// Round 3
// baseline (206.105 us; speedup 1.0000x reference)
//
#include <hip/hip_runtime.h>

#define T_DIM 2048
#define F_DIM 16
#define B_DIM 1024
#define STEPS 300
#define BPB 4   // batches per block in kA

// ws layout:
//   cbuf   @ 0     : float c[j*1024 + b]          (16 KB)
//   validw @ 16384 : u64 validw[j*5 + w]          (160 B)
#define OFF_VALID 16384u

// kA: per block, 4 batches: compute c_j, stage feats 10..13 (t<300) in LDS,
// ballot per-wave valid words, OR across the 4 batches in registers, one
// atomicOr per (j, wave) per block into validw (pre-zeroed by memset node).
__global__ void __launch_bounds__(320) kA(const float* __restrict__ x,
                                          const float* __restrict__ wptr,
                                          float* __restrict__ cbuf,
                                          unsigned long long* __restrict__ validw) {
#pragma clang fp contract(off)
    __shared__ float sF[4][STEPS];
    __shared__ float sc[4];
    int t = threadIdx.x;
    int wv = t >> 6;                       // wave index 0..4 => i-range [64*wv, 64*wv+63]
    unsigned long long acc[4] = {0ull, 0ull, 0ull, 0ull};

#pragma unroll
    for (int s = 0; s < BPB; ++s) {
        int b = blockIdx.x * BPB + s;
        if (t == 0) {                      // per-batch constants from x_last row
            const float* xl = x + ((size_t)b * T_DIM + (T_DIM - 1)) * F_DIM;
            float w = *wptr;
            float d = 0.0f;
#pragma unroll
            for (int j0 = 0; j0 < 4; ++j0) {
                d = d + xl[j0];                      // sequential prefix sum == np.sum
                float den = w + xl[5 + j0] * 25.0f;  // no FMA (contract off)
                float td  = (d * 150.0f) / den;      // IEEE div
                float c   = td * 10.0f;
                sc[j0] = c;
                cbuf[j0 * B_DIM + b] = c;
            }
        }
        if (t < STEPS) {
            const float* row = x + ((size_t)b * T_DIM + t) * F_DIM;
            float2 p0 = *(const float2*)(row + 10);  // feats 10,11
            float2 p1 = *(const float2*)(row + 12);  // feats 12,13
            sF[0][t] = p0.x; sF[1][t] = p0.y; sF[2][t] = p1.x; sF[3][t] = p1.y;
        }
        __syncthreads();
        bool act = t < STEPS;
#pragma unroll
        for (int j = 0; j < 4; ++j) {
            bool bit = false;
            if (act) {
                float r = (float)t - sc[j];          // same f32 rounding as ref
                int idx = (int)r;                    // trunc == astype(int32)
                idx = idx < 0 ? 0 : (idx > STEPS - 1 ? STEPS - 1 : idx);  // c>=0
                bit = sF[j][idx] != 0.0f;
            }
            acc[j] |= __ballot(bit);
        }
        __syncthreads();                   // before next s overwrites sF/sc
    }
    if ((t & 63) == 0) {
#pragma unroll
        for (int j = 0; j < 4; ++j)
            if (acc[j]) atomicOr(&validw[j * 5 + wv], acc[j]);
    }
}

// kC: per (b,i) pick first valid j, gather directly from x (L3-resident region).
__global__ void __launch_bounds__(256) kC(const float* __restrict__ x,
                                          const float* __restrict__ cbuf,
                                          const unsigned long long* __restrict__ validw,
                                          float* __restrict__ out) {
#pragma clang fp contract(off)
    int g = blockIdx.x * 256 + threadIdx.x;
    if (g >= B_DIM * STEPS) return;
    int b = g / STEPS;
    int i = g - b * STEPS;
    int wi = i >> 6, bi = i & 63;
    unsigned m = 0;
#pragma unroll
    for (int j = 0; j < 4; ++j)
        m |= (unsigned)((validw[j * 5 + wi] >> bi) & 1ull) << j;
    float r = 0.0f;
    if (m) {
        int j = __ffs(m) - 1;              // argmax of bool row == first True
        float c = cbuf[j * B_DIM + b];
        float rr = (float)i - c;
        int idx = (int)rr;
        idx = idx < 0 ? 0 : (idx > STEPS - 1 ? STEPS - 1 : idx);
        r = x[((size_t)b * T_DIM + idx) * F_DIM + 10 + j];
    }
    out[g] = r;
}

extern "C" void kernel_launch(void* const* d_in, const int* in_sizes, int n_in,
                              void* d_out, int out_size, void* d_ws, size_t ws_size,
                              hipStream_t stream) {
    const float* x    = (const float*)d_in[3];
    const float* wptr = (const float*)d_in[4];
    float* out = (float*)d_out;  // (1024, 300) row-major

    float*              cbuf   = (float*)d_ws;
    unsigned long long* validw = (unsigned long long*)((char*)d_ws + OFF_VALID);

    hipMemsetAsync(validw, 0, 20 * sizeof(unsigned long long), stream);
    hipLaunchKernelGGL(kA, dim3(B_DIM / BPB), dim3(320), 0, stream, x, wptr, cbuf, validw);
    hipLaunchKernelGGL(kC, dim3((B_DIM * STEPS + 255) / 256), dim3(256), 0, stream,
                       x, cbuf, validw, out);
}